// Round 11
// baseline (18.350 us; speedup 1.0000x reference)
//
#include <hip/hip_runtime.h>
#include <math.h>

// Problem constants (from reference)
#define BB 16
#define CC 3
#define OO 32
#define HH 128
#define WW 128
#define OH 124
#define OW 124
#define NPIX (OH * OW)          // 15376
#define NG   (NPIX / 4)         // 3844 4-pixel groups
#define GW   (OW / 4)           // 31 groups per output row
#define KF 25.0f

#define TPB  512
#define NBLK 481                // ceil(3844/8) chunks of 8 pix4 groups (32 pixels)

#if defined(__has_builtin)
#if __has_builtin(__builtin_amdgcn_sqrtf)
#define FSQRT(x) __builtin_amdgcn_sqrtf(x)
#else
#define FSQRT(x) sqrtf(x)
#endif
#else
#define FSQRT(x) sqrtf(x)
#endif

// exp(-0.5 z^2) = exp2(-(z*K2)^2), K2 = sqrt(0.5/ln2)
#define K2EXP 0.84932180f
#if defined(__has_builtin)
#if __has_builtin(__builtin_amdgcn_exp2f)
#define FEXP2(x) __builtin_amdgcn_exp2f(x)
#else
#define FEXP2(x) exp2f(x)
#endif
#else
#define FEXP2(x) exp2f(x)
#endif

// ---------------------------------------------------------------------------
// ONE kernel. Block owns 32 pixels (8 pix4 groups) x all (16 b, 32 o).
//   t = b*32 + og*8 + p4   (b: 0..15, og: 0..3 -> 8 o each, p4: 0..7)
// Phase 0: window sums from x -> LDS           (384 threads; t<96 preload W)
// Phase 1: dist partials, dist[8][4] in VGPRs  (512 threads)
// Phase 2: per-pixel unbiased 1/std (double)   (128 + 32 threads)
// Phase 3: out = exp2(-(d*isd')^2)             (512 threads, float4 stores;
//          per wave-store: 8 planes x 128 B contiguous -> L2 merges lines)
// Block->pixel mapping XCD-swizzled (bijective, 481 = 61 + 7*60).
// Last chunk (480) covers g 3840..3847; g >= 3844 guarded out.
// ---------------------------------------------------------------------------
__global__ __launch_bounds__(TPB, 2)
void fused_one(const float* __restrict__ x,
               const float* __restrict__ wgt,
               float* __restrict__ out) {
    __shared__ float  sS1[BB * CC][33];    // 6.3 KB
    __shared__ float  sS2[BB * CC][33];    // 6.3 KB
    __shared__ float  sPS[BB * 4][33];     // 8.4 KB
    __shared__ float  sPQ[BB * 4][33];     // 8.4 KB
    __shared__ float  sW[OO * CC];
    __shared__ float  sInv[32];
    __shared__ double sRm[32][4];
    __shared__ double sRq[32][4];

    const int t = threadIdx.x;

    // Bijective XCD swizzle: 481 = 61 + 7*60 (xcd0 gets 61 chunks).
    const int orig = blockIdx.x;
    const int xcd  = orig & 7;
    const int loc  = orig >> 3;
    const int chunk = ((xcd == 0) ? 0 : 61 + (xcd - 1) * 60) + loc;
    const int g0 = chunk * 8;              // first pix4 group (8 per block)

    // ---------------- Phase 0: weights + window sums ----------------
    if (t < OO * CC) sW[t] = wgt[t];       // 96 weights
    if (t < BB * CC * 8) {                 // 384 active
        int bc = t >> 3;                   // 0..47
        int p4 = t & 7;                    // 0..7
        int g  = g0 + p4;
        if (g < NG) {
            int i  = g / GW;
            int j0 = (g % GW) * 4;
            const float* img = x + (size_t)bc * (HH * WW);
            float S1[4] = {0, 0, 0, 0}, S2[4] = {0, 0, 0, 0};
#pragma unroll
            for (int di = 0; di < 5; ++di) {
                const float4* rp = reinterpret_cast<const float4*>(img + (i + di) * WW + j0);
                float4 lo = rp[0], hi = rp[1];
                float v[8] = {lo.x, lo.y, lo.z, lo.w, hi.x, hi.y, hi.z, hi.w};
                float q[8];
#pragma unroll
                for (int k = 0; k < 8; ++k) q[k] = v[k] * v[k];
                float r  = v[0] + v[1] + v[2] + v[3] + v[4];
                float rq = q[0] + q[1] + q[2] + q[3] + q[4];
                S1[0] += r;  S2[0] += rq;
#pragma unroll
                for (int u = 1; u < 4; ++u) {
                    r  += v[u + 4] - v[u - 1];
                    rq += q[u + 4] - q[u - 1];
                    S1[u] += r;  S2[u] += rq;
                }
            }
#pragma unroll
            for (int u = 0; u < 4; ++u) {
                sS1[bc][p4 * 4 + u] = S1[u];
                sS2[bc][p4 * 4 + u] = S2[u];
            }
        } else {
            // keep LDS defined for the tail block
#pragma unroll
            for (int u = 0; u < 4; ++u) {
                sS1[bc][p4 * 4 + u] = 0.0f;
                sS2[bc][p4 * 4 + u] = 0.0f;
            }
        }
    }
    __syncthreads();

    // ---------------- Phase 1: dist partials (dist stays in registers) ----
    const int b  = t >> 5;        // 0..15
    const int og = (t >> 3) & 3;  // 0..3  (8 o's each)
    const int p4 = t & 7;         // 0..7  (4 pixels each)

    float S1c[CC][4], S2c[CC][4];
#pragma unroll
    for (int c = 0; c < CC; ++c) {
#pragma unroll
        for (int u = 0; u < 4; ++u) {
            S1c[c][u] = sS1[b * CC + c][p4 * 4 + u];
            S2c[c][u] = sS2[b * CC + c][p4 * 4 + u];
        }
    }

    float dist[8][4];
    float sum[4] = {0, 0, 0, 0}, sq[4] = {0, 0, 0, 0};
#pragma unroll
    for (int oo = 0; oo < 8; ++oo) {
        int o = og * 8 + oo;
        float d[4] = {0, 0, 0, 0};
#pragma unroll
        for (int c = 0; c < CC; ++c) {
            float w  = sW[o * CC + c];
            float tw = 2.0f * w;
            float kw = KF * w * w;
#pragma unroll
            for (int u = 0; u < 4; ++u) {
                float inner = S2c[c][u] - tw * S1c[c][u] + kw;
                d[u] += FSQRT(fmaxf(inner, 0.0f));
            }
        }
#pragma unroll
        for (int u = 0; u < 4; ++u) {
            dist[oo][u] = d[u];
            sum[u] += d[u];
            sq[u]  += d[u] * d[u];
        }
    }
#pragma unroll
    for (int u = 0; u < 4; ++u) {
        sPS[b * 4 + og][p4 * 4 + u] = sum[u];
        sPQ[b * 4 + og][p4 * 4 + u] = sq[u];
    }
    __syncthreads();

    // ---------------- Phase 2: per-pixel 1/std (double) ----------------
    if (t < 128) {
        int pix = t >> 2;   // 0..31
        int seg = t & 3;    // 0..3, 16 rows each
        double sm = 0.0, sQ = 0.0;
#pragma unroll
        for (int k = 0; k < 16; ++k) {
            sm += (double)sPS[seg * 16 + k][pix];
            sQ += (double)sPQ[seg * 16 + k][pix];
        }
        sRm[pix][seg] = sm;
        sRq[pix][seg] = sQ;
    }
    __syncthreads();
    if (t < 32) {
        double sm = sRm[t][0] + sRm[t][1] + sRm[t][2] + sRm[t][3];
        double sQ = sRq[t][0] + sRq[t][1] + sRq[t][2] + sRq[t][3];
        const double n = (double)(BB * OO);
        double mean = sm / n;
        double var = (sQ - n * mean * mean) / (n - 1.0);
        if (var < 0.0) var = 0.0;
        // fold exp constant: exp(-0.5 z^2) = exp2(-(z*K2EXP)^2)
        sInv[t] = (float)(K2EXP / sqrt(var));
    }
    __syncthreads();

    // ---------------- Phase 3: output (plain f4 stores, L2 merges) -------
    float isd[4];
#pragma unroll
    for (int u = 0; u < 4; ++u) isd[u] = sInv[p4 * 4 + u];
    const bool valid = (g0 + p4) < NG;
    const size_t pixbase = (size_t)(g0 + p4) * 4;

#pragma unroll
    for (int oo = 0; oo < 8; ++oo) {
        int o = og * 8 + oo;
        float4 r;
        float z0 = dist[oo][0] * isd[0]; r.x = FEXP2(-(z0 * z0));
        float z1 = dist[oo][1] * isd[1]; r.y = FEXP2(-(z1 * z1));
        float z2 = dist[oo][2] * isd[2]; r.z = FEXP2(-(z2 * z2));
        float z3 = dist[oo][3] * isd[3]; r.w = FEXP2(-(z3 * z3));
        if (valid) {
            *reinterpret_cast<float4*>(&out[(size_t)(b * OO + o) * NPIX + pixbase]) = r;
        }
    }
}

// ---------------------------------------------------------------------------
extern "C" void kernel_launch(void* const* d_in, const int* in_sizes, int n_in,
                              void* d_out, int out_size, void* d_ws, size_t ws_size,
                              hipStream_t stream) {
    const float* x   = (const float*)d_in[0];   // (16,3,128,128)
    const float* wgt = (const float*)d_in[1];   // (32,3)
    float* out = (float*)d_out;                 // (16,32,124,124)

    fused_one<<<NBLK, TPB, 0, stream>>>(x, wgt, out);
}